// Round 12
// baseline (206.761 us; speedup 1.0000x reference)
//
#include <hip/hip_runtime.h>
#include <hip/hip_bf16.h>

// Kuramoto V2: B=8, N=2048, D=256, 50 steps.
//  1) normalize embeddings -> bf16 En
//  2) ONE persistent kernel: each block (64 rows x batch) BUILDS its own 64
//     C-rows (clip(En En^T,0) -> fp8) straight into LDS via bf16 MFMA
//     (swapped operands => per-thread 4 consecutive j => u32 LDS writes),
//     then iterates all 50 steps from LDS. No global C at all.
// Sync (R10, proven): "data as the message" msg u32 = stamp<<16|sin8<<8|cos8,
// relaxed agent atomics, parity dbuf, exact stamp match. ~2.8us/step.
// Grid dim3(B,BPB): linear%8 = batch -> per-batch XCD affinity (perf only),
// so prologue En streams are L2-resident (1 MB/batch vs 4 MB L2).

constexpr int B = 8;
constexpr int N = 2048;
constexpr int D = 256;
constexpr int STEPS = 50;
constexpr int ROWS = 64;            // C-rows per block
constexpr int BPB  = 32;            // blocks per batch
constexpr int TPB  = 512;           // threads per block
constexpr float DT = 0.01f;
constexpr float K_OVER_N = 1.0f / 2048.0f;
constexpr float TWO_PI_F = 6.2831854820251465f; // float(2*pi)

using bf16x8 = __attribute__((ext_vector_type(8))) short;
using f32x4  = __attribute__((ext_vector_type(4))) float;

static __device__ __forceinline__ unsigned short f2bf(float f) {
    union { float f; unsigned int i; } v; v.f = f;
    unsigned int x = v.i;
    x += 0x7fffu + ((x >> 16) & 1u);   // RNE
    return (unsigned short)(x >> 16);
}
static __device__ __forceinline__ unsigned char f2fp8(float f) {
    return (unsigned char)(__builtin_amdgcn_cvt_pk_fp8_f32(f, f, 0, false) & 0xff);
}

// ---------------- normalize: one wave per row of 256 floats -> bf16 -------
__global__ void normalize_k(const float* __restrict__ emb,
                            unsigned short* __restrict__ En) {
    const int row  = blockIdx.x * 4 + (threadIdx.x >> 6);
    const int lane = threadIdx.x & 63;
    const float4 v = *(const float4*)(emb + (size_t)row * D + lane * 4);
    float ss = v.x * v.x + v.y * v.y + v.z * v.z + v.w * v.w;
    #pragma unroll
    for (int k = 32; k >= 1; k >>= 1) ss += __shfl_xor(ss, k);
    const float inv = 1.0f / fmaxf(sqrtf(ss), 1e-12f);
    ushort4 o;
    o.x = f2bf(v.x * inv); o.y = f2bf(v.y * inv);
    o.z = f2bf(v.z * inv); o.w = f2bf(v.w * inv);
    *(ushort4*)(En + (size_t)row * D + lane * 4) = o;
}

// ---------------- persistent 50-step kernel --------------------------------
// Block = 64 rows of one batch, 8 waves. Prologue: build own C-rows in LDS.
//   mfma(A=En[j-rows], B=En[own-rows]): D col=lane&15 <-> own-row,
//   row=(lane>>4)*4+reg <-> j  => thread has 4 consecutive j at fixed own-row
//   => pack 4 fp8 -> u32 write at s_C[io][jb], swizzle (jb ^ ((io&7)<<4)).
// Main loop (unchanged R10): poll msg -> LDS tables -> dual fp8 MFMA matvec
//   -> finalize -> publish.
__global__ __launch_bounds__(512, 2) void fused_steps_k(
        const unsigned short* __restrict__ En,
        const float* __restrict__ theta0,
        float* __restrict__ out,
        const float* __restrict__ omega,
        unsigned int* __restrict__ msg) {
    __shared__ unsigned char s_C[ROWS * 2048];     // 128 KB, swizzled fp8
    __shared__ unsigned char s_tbl[2080 + 2048];   // cos | pad32 | sin
    __shared__ f32x4 s_acc[8][8];                  // [wave][g*2+col]

    const int b  = blockIdx.x;        // batch (fastest -> XCD affinity)
    const int rt = blockIdx.y;        // 0..31: rows rt*64..rt*64+63
    const int t  = threadIdx.x;
    const int w = t >> 6, lane = t & 63;
    const int col = lane & 15, g = lane >> 4;
    const int grp = w >> 1, kh = w & 1;

    // ---- per-row register state (t < 64) + init publish (stamp 1) ----
    float th = 0.f, sth = 0.f, cth = 0.f, om = 0.f;
    if (t < ROWS) {
        th = theta0[(size_t)b * N + rt * ROWS + t];
        om = omega[rt * ROWS + t];
        sth = __sinf(th); cth = __cosf(th);
        const unsigned int m = (1u << 16) |
            ((unsigned int)f2fp8(sth) << 8) | (unsigned int)f2fp8(cth);
        __hip_atomic_store(&msg[(size_t)b * N + rt * ROWS + t], m,
                           __ATOMIC_RELAXED, __HIP_MEMORY_SCOPE_AGENT);
    }

    // ---- prologue: build my 64 C-rows into LDS from En (bit-identical to
    //      the old build_c_k: same mfma, same k-order, same fp8 pack) ----
    {
        const unsigned short* EnB = En + (size_t)b * N * D;
        const int fr = lane & 15;
        const int fq = lane >> 4;
        bf16x8 bf[4][8];                          // own-panel frags, 128 VGPR
        #pragma unroll
        for (int gi = 0; gi < 4; ++gi)
            #pragma unroll
            for (int kc = 0; kc < 8; ++kc)
                bf[gi][kc] = *(const bf16x8*)(EnB +
                    (size_t)(rt * ROWS + gi * 16 + fr) * D + kc * 32 + fq * 8);
        for (int jt = w * 16; jt < w * 16 + 16; ++jt) {   // 16 j-tiles/wave
            f32x4 acc[4];
            #pragma unroll
            for (int gi = 0; gi < 4; ++gi)
                acc[gi] = (f32x4){0.f, 0.f, 0.f, 0.f};
            #pragma unroll
            for (int kc = 0; kc < 8; ++kc) {
                const bf16x8 A = *(const bf16x8*)(EnB +
                    (size_t)(jt * 16 + fr) * D + kc * 32 + fq * 8);
                #pragma unroll
                for (int gi = 0; gi < 4; ++gi)
                    acc[gi] = __builtin_amdgcn_mfma_f32_16x16x32_bf16(A, bf[gi][kc], acc[gi], 0, 0, 0);
            }
            #pragma unroll
            for (int gi = 0; gi < 4; ++gi) {
                int wpk = __builtin_amdgcn_cvt_pk_fp8_f32(fmaxf(acc[gi][0], 0.f),
                                                          fmaxf(acc[gi][1], 0.f), 0, false);
                wpk = __builtin_amdgcn_cvt_pk_fp8_f32(fmaxf(acc[gi][2], 0.f),
                                                      fmaxf(acc[gi][3], 0.f), wpk, true);
                const int io = gi * 16 + fr;
                const int jb = jt * 16 + fq * 4;
                *(unsigned int*)(s_C + io * 2048 + (jb ^ ((io & 7) << 4))) = (unsigned int)wpk;
            }
        }
    }
    __syncthreads();

    const unsigned char* Abase = s_C + (grp * 16 + col) * 2048;
    const unsigned int sw = (unsigned)((col & 7) << 4);
    const int tblbase = (col == 1) ? 2080 : 0;    // col1 -> sin; else cos
    const int o0 = kh * 1024 + g * 8;
    const int r0 = t * 4;                         // 4 rows polled per thread

    for (int s = 0; s < STEPS; ++s) {
        // ---- consume: poll 4 payload dwords until stamp == s+1 ----
        const unsigned int* mb = msg + ((size_t)(s & 1) * B + b) * N + r0;
        const unsigned int tgt = (unsigned int)(s + 1);
        unsigned int g0, g1, g2, g3;
        for (;;) {
            g0 = __hip_atomic_load(mb + 0, __ATOMIC_RELAXED, __HIP_MEMORY_SCOPE_AGENT);
            g1 = __hip_atomic_load(mb + 1, __ATOMIC_RELAXED, __HIP_MEMORY_SCOPE_AGENT);
            g2 = __hip_atomic_load(mb + 2, __ATOMIC_RELAXED, __HIP_MEMORY_SCOPE_AGENT);
            g3 = __hip_atomic_load(mb + 3, __ATOMIC_RELAXED, __HIP_MEMORY_SCOPE_AGENT);
            if (((g0 >> 16) == tgt) & ((g1 >> 16) == tgt) &
                ((g2 >> 16) == tgt) & ((g3 >> 16) == tgt)) break;
            __builtin_amdgcn_s_sleep(1);
        }
        // unpack payload straight into LDS tables (4 cos + 4 sin bytes)
        const unsigned int uc = (g0 & 0xffu) | ((g1 & 0xffu) << 8) |
                                ((g2 & 0xffu) << 16) | ((g3 & 0xffu) << 24);
        const unsigned int us = ((g0 >> 8) & 0xffu) | (((g1 >> 8) & 0xffu) << 8) |
                                (((g2 >> 8) & 0xffu) << 16) | (((g3 >> 8) & 0xffu) << 24);
        *(unsigned int*)(s_tbl + r0) = uc;
        *(unsigned int*)(s_tbl + 2080 + r0) = us;
        __syncthreads();

        // ---- dual matvec via fp8 MFMA, A from swizzled LDS, 2-acc ILP ----
        f32x4 acc0 = {0.f, 0.f, 0.f, 0.f}, acc1 = {0.f, 0.f, 0.f, 0.f};
        #pragma unroll
        for (int u = 0; u < 32; u += 2) {
            const int oa = o0 + u * 32;
            const long a0 = *(const long*)(Abase + (oa ^ sw));
            const long a1 = *(const long*)(Abase + ((oa + 32) ^ sw));
            long b0 = *(const long*)(s_tbl + tblbase + oa);
            long b1 = *(const long*)(s_tbl + tblbase + oa + 32);
            b0 = (col < 2) ? b0 : 0L;
            b1 = (col < 2) ? b1 : 0L;
            acc0 = __builtin_amdgcn_mfma_f32_16x16x32_fp8_fp8(a0, b0, acc0, 0, 0, 0);
            acc1 = __builtin_amdgcn_mfma_f32_16x16x32_fp8_fp8(a1, b1, acc1, 0, 0, 0);
        }
        acc0 += acc1;
        if (col < 2) s_acc[w][g * 2 + col] = acc0;
        __syncthreads();

        // ---- finalize rows (64 writers, all in wave 0): publish FIRST ----
        if (t < ROWS) {
            const int gr = t >> 4;                   // row-group
            const int gg = ((t & 15) >> 2) * 2;      // s_acc slot base
            const int rr = t & 3;                    // reg within frag
            float S1 = 0.f, S2 = 0.f;
            #pragma unroll
            for (int h = 0; h < 2; ++h) {            // two K-halves
                S1 += s_acc[gr * 2 + h][gg + 0][rr];
                S2 += s_acc[gr * 2 + h][gg + 1][rr];
            }
            const float csum = sth * S1 - cth * S2;
            th = th + DT * (om + K_OVER_N * csum);
            if (th >= TWO_PI_F) th -= TWO_PI_F;      // exact (Sterbenz) == fmodf
            if (s < STEPS - 1) {
                sth = __sinf(th); cth = __cosf(th);
                const unsigned int m = ((unsigned int)(s + 2) << 16) |
                    ((unsigned int)f2fp8(sth) << 8) | (unsigned int)f2fp8(cth);
                __hip_atomic_store(
                    &msg[((size_t)((s + 1) & 1) * B + b) * N + rt * ROWS + t],
                    m, __ATOMIC_RELAXED, __HIP_MEMORY_SCOPE_AGENT);
            } else {
                out[(size_t)b * N + rt * ROWS + t] = th;
            }
        }
    }
}

extern "C" void kernel_launch(void* const* d_in, const int* in_sizes, int n_in,
                              void* d_out, int out_size, void* d_ws, size_t ws_size,
                              hipStream_t stream) {
    const float* theta0 = (const float*)d_in[0];  // [B,N]
    const float* emb    = (const float*)d_in[1];  // [B,N,D]
    const float* omega  = (const float*)d_in[2];  // [N]
    float* out = (float*)d_out;                   // [B,N]

    // workspace layout (~8.1 MiB)
    unsigned short* En = (unsigned short*)d_ws;                    // B*N*D bf16
    unsigned int*  msg = (unsigned int*)(En + (size_t)B * N * D);  // 2*B*N u32

    normalize_k<<<B * N / 4, 256, 0, stream>>>(emb, En);

    fused_steps_k<<<dim3(B, BPB), TPB, 0, stream>>>(En, theta0, out, omega, msg);
}